// Round 3
// baseline (498.476 us; speedup 1.0000x reference)
//
#include <hip/hip_runtime.h>
#include <stdint.h>

typedef unsigned short u16;
typedef __bf16 bf16x8 __attribute__((ext_vector_type(8)));
typedef float f32x4 __attribute__((ext_vector_type(4)));

// Problem constants: B=16, N1=N2=2048, H=768, LAT=128, MID=256. All I/O fp32.
#define MM   32768   // B*N1 rows for all row-space GEMMs

// counted waits + raw barrier (T4): never drain vmcnt(0) in steady state.
#define WAITV(N) asm volatile("s_waitcnt vmcnt(" #N ")" ::: "memory")
#define WAITL0() asm volatile("s_waitcnt lgkmcnt(0)" ::: "memory")
#define BARR()   do { asm volatile("" ::: "memory"); __builtin_amdgcn_s_barrier(); \
                      asm volatile("" ::: "memory"); } while (0)

__device__ __forceinline__ u16 f2bf(float f) {
    uint32_t u; __builtin_memcpy(&u, &f, 4);
    u += 0x7fffu + ((u >> 16) & 1u);   // RNE
    return (u16)(u >> 16);
}

// async global->LDS, 16B per lane; LDS base must be wave-uniform (HW adds lane*16)
__device__ __forceinline__ void gl_lds16(const u16* g, u16* l) {
    __builtin_amdgcn_global_load_lds(
        (__attribute__((address_space(1))) void*)(g),
        (__attribute__((address_space(3))) void*)(l), 16, 0, 0);
}

// ---------------------------------------------------------------------------
// Weight transpose + fp32->bf16: wt[n*K + k] = bf16(W[k*N + n]); 507904 elems.
__global__ void transpose_all(const float* __restrict__ We1, const float* __restrict__ We2,
                              const float* __restrict__ Wq,  const float* __restrict__ Wk,
                              const float* __restrict__ Wv,  const float* __restrict__ Wd1,
                              const float* __restrict__ Wd2, u16* __restrict__ wt) {
    int i = blockIdx.x * 256 + threadIdx.x;
    const float* src; int K, N, off;
    if      (i < 196608) { src = We1; K = 768; N = 256; off = i;          }
    else if (i < 229376) { src = We2; K = 256; N = 128; off = i - 196608; }
    else if (i < 245760) { src = Wq;  K = 128; N = 128; off = i - 229376; }
    else if (i < 262144) { src = Wk;  K = 128; N = 128; off = i - 245760; }
    else if (i < 278528) { src = Wv;  K = 128; N = 128; off = i - 262144; }
    else if (i < 311296) { src = Wd1; K = 128; N = 256; off = i - 278528; }
    else if (i < 507904) { src = Wd2; K = 256; N = 768; off = i - 311296; }
    else return;
    int n = off / K, k = off % K;
    wt[i] = f2bf(src[(size_t)k * N + n]);
}

// ---------------------------------------------------------------------------
// C = act(A[M,K] @ Wt[N,K]^T + bias[N]); BMx128 tile, BK=64, 4 waves (2x2).
// Counted-vmcnt pipeline: issue stage(t+1) -> WAITV(6/8)+raw barrier (stage(t)
// complete, stage(t+1) STAYS IN FLIGHT) -> compute(t) -> raw barrier (WAR).
// __syncthreads was draining vmcnt(0), re-exposing staging latency each step.
template <int BM, int ACT, bool TRANS, bool A_F32, bool OUT_F32>
__global__ void gemm_bt(const void* __restrict__ Avp, const u16* __restrict__ Wt,
                        const float* __restrict__ bias, void* __restrict__ Cvp,
                        int M, int N, int K) {
    constexpr int MI  = BM / 32;      // 16-row fragments per wave
    constexpr int AF4 = BM / 16;      // float4 loads per thread (A_F32 path)
    __shared__ u16 a_sh[2][BM * 64];
    __shared__ u16 b_sh[2][128 * 64];
    const int t = threadIdx.x;
    const int wave = t >> 6, lane = t & 63;
    const int lrow = lane & 15, quad = lane >> 4;
    const int wr = wave >> 1, wc = wave & 1;
    const int m0 = blockIdx.x * BM, n0 = blockIdx.y * 128;

    const float* Af = (const float*)Avp;
    const u16*   Ab = (const u16*)Avp;

    f32x4 acc[MI][4];
#pragma unroll
    for (int i = 0; i < MI; i++)
#pragma unroll
        for (int j = 0; j < 4; j++) acc[i][j] = (f32x4){0.f, 0.f, 0.f, 0.f};

    float4 pf[A_F32 ? AF4 : 1];       // in-flight A tile (fp32 path)

    auto stage_b = [&](int buf, int k0) {
#pragma unroll
        for (int it = 0; it < 4; it++) {          // 128x64 bf16 = 1024 segs
            int s = it * 256 + t;
            gl_lds16(Wt + (size_t)(n0 + (s >> 3)) * K + k0 + (s & 7) * 8,
                     &b_sh[buf][(it * 256 + wave * 64) * 8]);
        }
    };
    auto stage_a_bf = [&](int buf, int k0) {
#pragma unroll
        for (int it = 0; it < BM / 32; it++) {    // BMx64 bf16 = BM*8 segs
            int s = it * 256 + t;
            gl_lds16(Ab + (size_t)(m0 + (s >> 3)) * K + k0 + (s & 7) * 8,
                     &a_sh[buf][(it * 256 + wave * 64) * 8]);
        }
    };
    auto load_a_f32 = [&](int k0) {               // issue only; no wait
#pragma unroll
        for (int it = 0; it < AF4; it++) {
            int s = it * 256 + t;
            pf[it] = *(const float4*)(Af + (size_t)(m0 + (s >> 4)) * K + k0 + (s & 15) * 4);
        }
    };
    auto write_a_f32 = [&](int buf) {             // convert + LDS write (late)
#pragma unroll
        for (int it = 0; it < AF4; it++) {
            int s = it * 256 + t;
            int row = s >> 4, kc = s & 15;
            float4 v = pf[it];
            uint32_t p0 = (uint32_t)f2bf(v.x) | ((uint32_t)f2bf(v.y) << 16);
            uint32_t p1 = (uint32_t)f2bf(v.z) | ((uint32_t)f2bf(v.w) << 16);
            *(uint32_t*)&a_sh[buf][row * 64 + kc * 4]     = p0;
            *(uint32_t*)&a_sh[buf][row * 64 + kc * 4 + 2] = p1;
        }
    };
    auto compute = [&](int buf) {
#pragma unroll
        for (int kk = 0; kk < 2; kk++) {
            bf16x8 af[MI], bfv[4];
#pragma unroll
            for (int i = 0; i < MI; i++)
                af[i] = *(const bf16x8*)&a_sh[buf][(wr * (BM / 2) + i * 16 + lrow) * 64 + kk * 32 + quad * 8];
#pragma unroll
            for (int j = 0; j < 4; j++)
                bfv[j] = *(const bf16x8*)&b_sh[buf][(wc * 64 + j * 16 + lrow) * 64 + kk * 32 + quad * 8];
            __builtin_amdgcn_s_setprio(1);
#pragma unroll
            for (int i = 0; i < MI; i++)
#pragma unroll
                for (int j = 0; j < 4; j++)
                    acc[i][j] = __builtin_amdgcn_mfma_f32_16x16x32_bf16(af[i], bfv[j], acc[i][j], 0, 0, 0);
            __builtin_amdgcn_s_setprio(0);
        }
    };

    const int T = K >> 6;
    // prologue: tile 0 -> buf 0 (full drain once)
    if (A_F32) {
        load_a_f32(0); stage_b(0, 0);
        WAITV(4);                       // A regs ready (B still in flight)
        write_a_f32(0);
        WAITL0(); WAITV(0);
    } else {
        stage_a_bf(0, 0); stage_b(0, 0);
        WAITV(0);
    }
    BARR();

    int cur = 0;
    for (int tt = 0; tt < T; ++tt) {
        const int nk = (tt + 1) * 64;
        const bool more = nk < K;
        if (more) {                     // issue next-tile stage (stays in flight)
            if (A_F32) load_a_f32(nk); else stage_a_bf(cur ^ 1, nk);
            stage_b(cur ^ 1, nk);
        }
        if (tt > 0) {                   // B1: stage(t) complete across all waves
            if (more) { if (A_F32) { WAITV(8); } else { WAITV(6); } }
            else      { WAITV(0); }
            BARR();
        }
        compute(cur);
        if (A_F32 && more) {            // T14 late write of next A tile
            WAITV(4);                   // next A regs ready (B(t+1) in flight)
            write_a_f32(cur ^ 1);
            WAITL0();
        }
        if (more) BARR();               // B2: reads of buf[cur] done (self-drained)
        cur ^= 1;
    }

    float bv4[4];
#pragma unroll
    for (int j = 0; j < 4; j++) bv4[j] = bias[n0 + wc * 64 + j * 16 + lrow];

#pragma unroll
    for (int i = 0; i < MI; i++) {
#pragma unroll
        for (int j = 0; j < 4; j++) {
            const int col = n0 + wc * 64 + j * 16 + lrow;
            if (!TRANS) {
#pragma unroll
                for (int r = 0; r < 4; r++) {
                    float x = acc[i][j][r] + bv4[j];
                    if (ACT == 1) x = fmaxf(x, 0.f);
                    if (ACT == 2) x = 1.f / (1.f + __expf(-x));
                    const int row = m0 + wr * (BM / 2) + i * 16 + quad * 4 + r;
                    if (OUT_F32) ((float*)Cvp)[(size_t)row * N + col] = x;
                    else         ((u16*)Cvp)[(size_t)row * N + col] = f2bf(x);
                }
            } else {
                u16 vv[4];
#pragma unroll
                for (int r = 0; r < 4; r++) vv[r] = f2bf(acc[i][j][r] + bv4[j]);
                // out[b][col][rowInBatch], batch = 2048 rows (BM | 2048, no straddle)
                u16* Cb = (u16*)Cvp;
                size_t base = (size_t)(m0 >> 11) * ((size_t)N * 2048) + (size_t)col * 2048 +
                              (m0 & 2047) + wr * (BM / 2) + i * 16 + quad * 4;
                *(uint32_t*)&Cb[base]     = (uint32_t)vv[0] | ((uint32_t)vv[1] << 16);
                *(uint32_t*)&Cb[base + 2] = (uint32_t)vv[2] | ((uint32_t)vv[3] << 16);
            }
        }
    }
}

// ---------------------------------------------------------------------------
// Flash attention: block = (batch, 64 Q rows); 32 KV tiles of 64; all bf16 in ws.
// LDS 64KB: K double-buffered (counted-vmcnt pipeline), V single, Q/P shared.
// XOR swizzle (T2, rule #21): physical = logical ^ ((row&7)<<4 bytes); applied
// via inverse-permuted global src (gl_lds writes linearly) + XOR on reads.
// Per-tile schedule (T4 counts, in-order vmcnt queue):
//   [A] issue K(t+1)->kb[c^1]   [B] WAITV(8)+bar  (K(t) ready; K(t+1)/V(t) fly)
//   [C] QK^T + softmax + P      [D] WAITV(4)+bar  (V(t) ready; K(t+1) flies)
//   [E] PV                      [F] bar; issue V(t+1)  (hides under next QK+SM)
__global__ __launch_bounds__(256)
void flash_attn(const u16* __restrict__ Q, const u16* __restrict__ Kb,
                const u16* __restrict__ VT, u16* __restrict__ O) {
    __shared__ u16 kb_sh[2][64 * 128];  // K tiles [kv][d] (swizzled)    32KB
    __shared__ u16 v_sh[128 * 64];      // V^T tile [d][kv] (swizzled)   16KB
    __shared__ u16 qp_sh[64 * 128];     // Q tile, then P (swizzled)     16KB

    const int t = threadIdx.x, wave = t >> 6, lane = t & 63;
    const int lrow = lane & 15, quad = lane >> 4;
    const int lsw = (lrow & 7) << 3;          // element-XOR for swizzled reads
    const int b = blockIdx.x >> 5, q0 = (blockIdx.x & 31) * 64;

    // hoisted per-thread staging offsets (loop-invariant)
    int ksrc[4], vsrc[4], ldst[4];
#pragma unroll
    for (int it = 0; it < 4; it++) {
        int s = it * 256 + t;
        ksrc[it] = (s ^ ((s >> 4) & 7)) * 8;          // K/Q: 16 segs/row swizzle
        int row = s >> 3, cc = (s & 7) ^ (row & 7);   // V^T: 8 segs/row swizzle
        vsrc[it] = row * 2048 + cc * 8;
        ldst[it] = (it * 256 + wave * 64) * 8;        // wave-uniform LDS base
    }

    const u16* qg  = Q  + (size_t)(b * 2048 + q0) * 128;
    const u16* kgb = Kb + (size_t)b * 2048 * 128;
    const u16* vgb = VT + (size_t)b * 262144;

    // prologue: issue Q(4), K0(4), V0(4); wait Q (K0/V0 stay in flight)
#pragma unroll
    for (int it = 0; it < 4; it++) gl_lds16(qg + ksrc[it], &qp_sh[ldst[it]]);
#pragma unroll
    for (int it = 0; it < 4; it++) gl_lds16(kgb + ksrc[it], &kb_sh[0][ldst[it]]);
#pragma unroll
    for (int it = 0; it < 4; it++) gl_lds16(vgb + vsrc[it], &v_sh[ldst[it]]);
    WAITV(8); BARR();
    bf16x8 qf[4];
#pragma unroll
    for (int ks = 0; ks < 4; ks++)
        qf[ks] = *(const bf16x8*)&qp_sh[(((wave * 16 + lrow) * 128) + ks * 32 + quad * 8) ^ lsw];

    f32x4 o_acc[8];
#pragma unroll
    for (int ct = 0; ct < 8; ct++) o_acc[ct] = (f32x4){0.f, 0.f, 0.f, 0.f};
    float m_i[4] = {-1e30f, -1e30f, -1e30f, -1e30f};
    float l_i[4] = {0.f, 0.f, 0.f, 0.f};

    for (int tile = 0; tile < 32; tile++) {
        const int c = tile & 1;
        // [A] issue next K (tile 31: in-bounds dummy reload of tile 0 keeps counts uniform)
        const u16* kg_n = kgb + (size_t)(((tile + 1) & 31) * 64) * 128;
#pragma unroll
        for (int it = 0; it < 4; it++) gl_lds16(kg_n + ksrc[it], &kb_sh[c ^ 1][ldst[it]]);
        // [B] K(t) ready everywhere; K(t+1) + V(t) remain in flight
        WAITV(8); BARR();

        // [C] S = Q @ K^T : wave computes 16 rows x 64 cols = 4 C-tiles
        f32x4 s_acc[4];
        __builtin_amdgcn_s_setprio(1);
#pragma unroll
        for (int ct = 0; ct < 4; ct++) {
            f32x4 a = (f32x4){0.f, 0.f, 0.f, 0.f};
#pragma unroll
            for (int ks = 0; ks < 4; ks++) {
                bf16x8 kf = *(const bf16x8*)&kb_sh[c][(((ct * 16 + lrow) * 128) + ks * 32 + quad * 8) ^ lsw];
                a = __builtin_amdgcn_mfma_f32_16x16x32_bf16(qf[ks], kf, a, 0, 0, 0);
            }
            s_acc[ct] = a;
        }
        __builtin_amdgcn_s_setprio(0);

        // online softmax: row = quad*4+r, reduce across the 16 lanes of the quad
        float mnew[4], alpha[4], ps[4];
#pragma unroll
        for (int r = 0; r < 4; r++) {
            float mx = s_acc[0][r];
#pragma unroll
            for (int ct = 1; ct < 4; ct++) mx = fmaxf(mx, s_acc[ct][r]);
#pragma unroll
            for (int d = 8; d >= 1; d >>= 1) mx = fmaxf(mx, __shfl_xor(mx, d, 64));
            mnew[r] = fmaxf(m_i[r], mx);
            alpha[r] = __expf(m_i[r] - mnew[r]);
            m_i[r] = mnew[r];
            ps[r] = 0.f;
        }
#pragma unroll
        for (int ct = 0; ct < 4; ct++)
#pragma unroll
            for (int r = 0; r < 4; r++) {
                float p = __expf(s_acc[ct][r] - mnew[r]);
                ps[r] += p;
                qp_sh[(((wave * 16 + quad * 4 + r) * 128) + ct * 16 + lrow) ^ (((quad * 4 + r) & 7) << 3)] = f2bf(p);
            }
#pragma unroll
        for (int r = 0; r < 4; r++) {
#pragma unroll
            for (int d = 8; d >= 1; d >>= 1) ps[r] += __shfl_xor(ps[r], d, 64);
            l_i[r] = l_i[r] * alpha[r] + ps[r];
        }
#pragma unroll
        for (int ct = 0; ct < 8; ct++)
#pragma unroll
            for (int r = 0; r < 4; r++) o_acc[ct][r] *= alpha[r];

        // [D] V(t) ready everywhere; K(t+1) remains in flight
        WAITV(4); BARR();

        // [E] O += P @ V ; P read back (wave-private rows, DS in-order)
        bf16x8 pfa[2];
#pragma unroll
        for (int ks = 0; ks < 2; ks++)
            pfa[ks] = *(const bf16x8*)&qp_sh[(((wave * 16 + lrow) * 128) + ks * 32 + quad * 8) ^ lsw];
        __builtin_amdgcn_s_setprio(1);
#pragma unroll
        for (int ct = 0; ct < 8; ct++)
#pragma unroll
            for (int ks = 0; ks < 2; ks++) {
                bf16x8 vf = *(const bf16x8*)&v_sh[(((ct * 16 + lrow) * 64) + ks * 32 + quad * 8) ^ lsw];
                o_acc[ct] = __builtin_amdgcn_mfma_f32_16x16x32_bf16(pfa[ks], vf, o_acc[ct], 0, 0, 0);
            }
        __builtin_amdgcn_s_setprio(0);

        // [F] PV reads drained (consumed by MFMA); then issue next V
        if (tile < 31) {
            BARR();
            const u16* vg_n = vgb + (tile + 1) * 64;
#pragma unroll
            for (int it = 0; it < 4; it++) gl_lds16(vg_n + vsrc[it], &v_sh[ldst[it]]);
        }
    }

    float inv_l[4];
#pragma unroll
    for (int r = 0; r < 4; r++) inv_l[r] = 1.f / l_i[r];
#pragma unroll
    for (int ct = 0; ct < 8; ct++)
#pragma unroll
        for (int r = 0; r < 4; r++) {
            const int row = b * 2048 + q0 + wave * 16 + quad * 4 + r;
            O[(size_t)row * 128 + ct * 16 + lrow] = f2bf(o_acc[ct][r] * inv_l[r]);
        }
}

// ---------------------------------------------------------------------------
extern "C" void kernel_launch(void* const* d_in, const int* in_sizes, int n_in,
                              void* d_out, int out_size, void* d_ws, size_t ws_size,
                              hipStream_t stream) {
    const float* mainf = (const float*)d_in[0];
    const float* feat  = (const float*)d_in[1];
    const float* We1 = (const float*)d_in[2];  const float* be1 = (const float*)d_in[3];
    const float* We2 = (const float*)d_in[4];  const float* be2 = (const float*)d_in[5];
    const float* Wq  = (const float*)d_in[6];  const float* bq  = (const float*)d_in[7];
    const float* Wk  = (const float*)d_in[8];  const float* bk  = (const float*)d_in[9];
    const float* Wv  = (const float*)d_in[10]; const float* bv  = (const float*)d_in[11];
    const float* Wd1 = (const float*)d_in[12]; const float* bd1 = (const float*)d_in[13];
    const float* Wd2 = (const float*)d_in[14]; const float* bd2 = (const float*)d_in[15];

    // ws layout (u16 elements), total 24,641,536 u16 = 49.3 MB
    u16* ws = (u16*)d_ws;
    u16* wt = ws;                 // 524288 (507904 used), transposed bf16 weights
    u16* h1 = wt + 524288;        // 32768x256 enc hidden / dec hidden (bf16)
    u16* mf = h1 + 8388608;       // 32768x128 m-latent, f-latent, then attn out
    u16* qb = mf + 4194304;       // 32768x128
    u16* kb = qb + 4194304;       // 32768x128
    u16* vT = kb + 4194304;       // [16][128][2048]
    u16* wt_e1 = wt, *wt_e2 = wt + 196608, *wt_q = wt + 229376, *wt_k = wt + 245760,
       * wt_v = wt + 262144, *wt_d1 = wt + 278528, *wt_d2 = wt + 311296;

    transpose_all<<<1984, 256, 0, stream>>>(We1, We2, Wq, Wk, Wv, Wd1, Wd2, wt);

    // encode(main): h1 = relu(main@We1+be1); m = relu(h1@We2+be2); q = m@Wq+bq
    gemm_bt<64, 1, false, true,  false><<<dim3(512, 2), 256, 0, stream>>>(mainf, wt_e1, be1, h1, MM, 256, 768);
    gemm_bt<64, 1, false, false, false><<<dim3(512, 1), 256, 0, stream>>>(h1,    wt_e2, be2, mf, MM, 128, 256);
    gemm_bt<64, 0, false, false, false><<<dim3(512, 1), 256, 0, stream>>>(mf,    wt_q,  bq,  qb, MM, 128, 128);
    // encode(feature): f; k = f@Wk+bk; vT = (f@Wv+bv)^T per batch
    gemm_bt<64, 1, false, true,  false><<<dim3(512, 2), 256, 0, stream>>>(feat, wt_e1, be1, h1, MM, 256, 768);
    gemm_bt<64, 1, false, false, false><<<dim3(512, 1), 256, 0, stream>>>(h1,   wt_e2, be2, mf, MM, 128, 256);
    gemm_bt<64, 0, false, false, false><<<dim3(512, 1), 256, 0, stream>>>(mf,   wt_k,  bk,  kb, MM, 128, 128);
    gemm_bt<64, 0, true,  false, false><<<dim3(512, 1), 256, 0, stream>>>(mf,   wt_v,  bv,  vT, MM, 128, 128);

    flash_attn<<<512, 256, 0, stream>>>(qb, kb, vT, mf);   // attn -> mf (k,v done)

    // decode: h1 = relu(attn@Wd1+bd1); out = sigmoid(h1@Wd2+bd2) -> fp32 d_out
    gemm_bt<64, 1, false, false, false><<<dim3(512, 2), 256, 0, stream>>>(mf, wt_d1, bd1, h1, MM, 256, 128);
    gemm_bt<64, 2, false, false, true ><<<dim3(512, 6), 256, 0, stream>>>(h1, wt_d2, bd2, d_out, MM, 768, 256);
}

// Round 6
// 492.194 us; speedup vs baseline: 1.0128x; 1.0128x over previous
//
#include <hip/hip_runtime.h>
#include <stdint.h>

typedef unsigned short u16;
typedef __bf16 bf16x8 __attribute__((ext_vector_type(8)));
typedef float f32x4 __attribute__((ext_vector_type(4)));

// Problem constants: B=16, N1=N2=2048, H=768, LAT=128, MID=256. All I/O fp32.
#define MM   32768   // B*N1 rows for all row-space GEMMs

// counted waits + raw barrier (T4)
#define WAITV(N) asm volatile("s_waitcnt vmcnt(" #N ")" ::: "memory")
#define WAITL0() asm volatile("s_waitcnt lgkmcnt(0)" ::: "memory")
#define BARR()   do { asm volatile("" ::: "memory"); __builtin_amdgcn_s_barrier(); \
                      asm volatile("" ::: "memory"); } while (0)

__device__ __forceinline__ u16 f2bf(float f) {
    uint32_t u; __builtin_memcpy(&u, &f, 4);
    u += 0x7fffu + ((u >> 16) & 1u);   // RNE
    return (u16)(u >> 16);
}

// async global->LDS, 16B per lane; LDS base must be wave-uniform (HW adds lane*16)
__device__ __forceinline__ void gl_lds16(const u16* g, u16* l) {
    __builtin_amdgcn_global_load_lds(
        (__attribute__((address_space(1))) void*)(g),
        (__attribute__((address_space(3))) void*)(l), 16, 0, 0);
}

// ---------------------------------------------------------------------------
// Weight transpose + fp32->bf16: wt[n*K + k] = bf16(W[k*N + n]); 507904 elems.
__global__ void transpose_all(const float* __restrict__ We1, const float* __restrict__ We2,
                              const float* __restrict__ Wq,  const float* __restrict__ Wk,
                              const float* __restrict__ Wv,  const float* __restrict__ Wd1,
                              const float* __restrict__ Wd2, u16* __restrict__ wt) {
    int i = blockIdx.x * 256 + threadIdx.x;
    const float* src; int K, N, off;
    if      (i < 196608) { src = We1; K = 768; N = 256; off = i;          }
    else if (i < 229376) { src = We2; K = 256; N = 128; off = i - 196608; }
    else if (i < 245760) { src = Wq;  K = 128; N = 128; off = i - 229376; }
    else if (i < 262144) { src = Wk;  K = 128; N = 128; off = i - 245760; }
    else if (i < 278528) { src = Wv;  K = 128; N = 128; off = i - 262144; }
    else if (i < 311296) { src = Wd1; K = 128; N = 256; off = i - 278528; }
    else if (i < 507904) { src = Wd2; K = 256; N = 768; off = i - 311296; }
    else return;
    int n = off / K, k = off % K;
    wt[i] = f2bf(src[(size_t)k * N + n]);
}

// ---------------------------------------------------------------------------
// Small streaming GEMM for K<=256, N*K<=32768: W lives ENTIRELY in LDS
// (XOR-swizzled rows), staged once per block; then each wave independently
// computes one 16-row strip with ZERO barriers: A global->VGPR (16 rows x
// 64B lines, coalesced), MFMA against LDS W, store. 256 blocks x 8 waves
// = 2048 strips = 32768 rows. The old K-loop structure was latency-bound
// at K=128-256 (2-4 iterations of all-prologue, lockstep barriers).
template <int N, int K, int ACT, bool TRANS>
__global__ __launch_bounds__(512)
void gemm_small(const u16* __restrict__ A, const u16* __restrict__ Wt,
                const float* __restrict__ bias, u16* __restrict__ C) {
    __shared__ u16 w_sh[N * K];                   // <= 64KB, swizzled
    const int t = threadIdx.x, wave = t >> 6, lane = t & 63;
    const int lrow = lane & 15, quad = lane >> 4;
    constexpr int SEGS = N * K / 8;               // 16B segments

    // stage W: phys elem = logical ^ ((n&7)<<3)  (both-sides swizzle, reg path)
    for (int s = t; s < SEGS; s += 512) {
        int n = s / (K / 8), kc = s % (K / 8);
        bf16x8 w = *(const bf16x8*)&Wt[(size_t)n * K + kc * 8];
        *(bf16x8*)&w_sh[(n * K + kc * 8) ^ ((n & 7) << 3)] = w;
    }
    float bv[N / 16];
#pragma unroll
    for (int j = 0; j < N / 16; j++) bv[j] = bias[j * 16 + lrow];
    __syncthreads();

    const int strip = blockIdx.x * 8 + wave;      // wave-private 16-row strip
    const int row0 = strip * 16;

    bf16x8 af[K / 32];
#pragma unroll
    for (int ks = 0; ks < K / 32; ks++)
        af[ks] = *(const bf16x8*)&A[(size_t)(row0 + lrow) * K + ks * 32 + quad * 8];

    f32x4 acc[N / 16];
#pragma unroll
    for (int j = 0; j < N / 16; j++) acc[j] = (f32x4){0.f, 0.f, 0.f, 0.f};
#pragma unroll
    for (int j = 0; j < N / 16; j++)
#pragma unroll
        for (int ks = 0; ks < K / 32; ks++) {
            bf16x8 wf = *(const bf16x8*)&w_sh[((j * 16 + lrow) * K + ks * 32 + quad * 8) ^ ((lrow & 7) << 3)];
            acc[j] = __builtin_amdgcn_mfma_f32_16x16x32_bf16(af[ks], wf, acc[j], 0, 0, 0);
        }

#pragma unroll
    for (int j = 0; j < N / 16; j++) {
        const int col = j * 16 + lrow;
        if (!TRANS) {
#pragma unroll
            for (int r = 0; r < 4; r++) {
                float x = acc[j][r] + bv[j];
                if (ACT == 1) x = fmaxf(x, 0.f);
                C[(size_t)(row0 + quad * 4 + r) * N + col] = f2bf(x);
            }
        } else {
            u16 vv[4];
#pragma unroll
            for (int r = 0; r < 4; r++) vv[r] = f2bf(acc[j][r] + bv[j]);
            // out[b][col][rowInBatch], batch = 2048 rows (strips never straddle)
            size_t base = (size_t)(row0 >> 11) * ((size_t)N * 2048) + (size_t)col * 2048 +
                          (row0 & 2047) + quad * 4;
            *(uint32_t*)&C[base]     = (uint32_t)vv[0] | ((uint32_t)vv[1] << 16);
            *(uint32_t*)&C[base + 2] = (uint32_t)vv[2] | ((uint32_t)vv[3] << 16);
        }
    }
}

// ---------------------------------------------------------------------------
// C = act(A[M,K] @ Wt[N,K]^T + bias[N]); BMx128 tile, BK=64, 4 waves (2x2).
// Counted-vmcnt pipeline (stage t+1 in flight across barriers). Used only for
// the two big-K gemms (enc1 K=768 fp32-A, dec2 N=768) where W won't fit LDS.
template <int BM, int ACT, bool TRANS, bool A_F32, bool OUT_F32>
__global__ void gemm_bt(const void* __restrict__ Avp, const u16* __restrict__ Wt,
                        const float* __restrict__ bias, void* __restrict__ Cvp,
                        int M, int N, int K) {
    constexpr int MI  = BM / 32;      // 16-row fragments per wave
    constexpr int AF4 = BM / 16;      // float4 loads per thread (A_F32 path)
    __shared__ u16 a_sh[2][BM * 64];
    __shared__ u16 b_sh[2][128 * 64];
    const int t = threadIdx.x;
    const int wave = t >> 6, lane = t & 63;
    const int lrow = lane & 15, quad = lane >> 4;
    const int wr = wave >> 1, wc = wave & 1;
    const int m0 = blockIdx.x * BM, n0 = blockIdx.y * 128;

    const float* Af = (const float*)Avp;
    const u16*   Ab = (const u16*)Avp;

    f32x4 acc[MI][4];
#pragma unroll
    for (int i = 0; i < MI; i++)
#pragma unroll
        for (int j = 0; j < 4; j++) acc[i][j] = (f32x4){0.f, 0.f, 0.f, 0.f};

    float4 pf[A_F32 ? AF4 : 1];       // in-flight A tile (fp32 path)

    auto stage_b = [&](int buf, int k0) {
#pragma unroll
        for (int it = 0; it < 4; it++) {          // 128x64 bf16 = 1024 segs
            int s = it * 256 + t;
            gl_lds16(Wt + (size_t)(n0 + (s >> 3)) * K + k0 + (s & 7) * 8,
                     &b_sh[buf][(it * 256 + wave * 64) * 8]);
        }
    };
    auto stage_a_bf = [&](int buf, int k0) {
#pragma unroll
        for (int it = 0; it < BM / 32; it++) {    // BMx64 bf16 = BM*8 segs
            int s = it * 256 + t;
            gl_lds16(Ab + (size_t)(m0 + (s >> 3)) * K + k0 + (s & 7) * 8,
                     &a_sh[buf][(it * 256 + wave * 64) * 8]);
        }
    };
    auto load_a_f32 = [&](int k0) {               // issue only; no wait
#pragma unroll
        for (int it = 0; it < AF4; it++) {
            int s = it * 256 + t;
            pf[it] = *(const float4*)(Af + (size_t)(m0 + (s >> 4)) * K + k0 + (s & 15) * 4);
        }
    };
    auto write_a_f32 = [&](int buf) {             // convert + LDS write (late)
#pragma unroll
        for (int it = 0; it < AF4; it++) {
            int s = it * 256 + t;
            int row = s >> 4, kc = s & 15;
            float4 v = pf[it];
            uint32_t p0 = (uint32_t)f2bf(v.x) | ((uint32_t)f2bf(v.y) << 16);
            uint32_t p1 = (uint32_t)f2bf(v.z) | ((uint32_t)f2bf(v.w) << 16);
            *(uint32_t*)&a_sh[buf][row * 64 + kc * 4]     = p0;
            *(uint32_t*)&a_sh[buf][row * 64 + kc * 4 + 2] = p1;
        }
    };
    auto compute = [&](int buf) {
#pragma unroll
        for (int kk = 0; kk < 2; kk++) {
            bf16x8 af[MI], bfv[4];
#pragma unroll
            for (int i = 0; i < MI; i++)
                af[i] = *(const bf16x8*)&a_sh[buf][(wr * (BM / 2) + i * 16 + lrow) * 64 + kk * 32 + quad * 8];
#pragma unroll
            for (int j = 0; j < 4; j++)
                bfv[j] = *(const bf16x8*)&b_sh[buf][(wc * 64 + j * 16 + lrow) * 64 + kk * 32 + quad * 8];
            __builtin_amdgcn_s_setprio(1);
#pragma unroll
            for (int i = 0; i < MI; i++)
#pragma unroll
                for (int j = 0; j < 4; j++)
                    acc[i][j] = __builtin_amdgcn_mfma_f32_16x16x32_bf16(af[i], bfv[j], acc[i][j], 0, 0, 0);
            __builtin_amdgcn_s_setprio(0);
        }
    };

    const int T = K >> 6;
    // prologue: tile 0 -> buf 0 (full drain once)
    if (A_F32) {
        load_a_f32(0); stage_b(0, 0);
        WAITV(4);                       // A regs ready (B still in flight)
        write_a_f32(0);
        WAITL0(); WAITV(0);
    } else {
        stage_a_bf(0, 0); stage_b(0, 0);
        WAITV(0);
    }
    BARR();

    int cur = 0;
    for (int tt = 0; tt < T; ++tt) {
        const int nk = (tt + 1) * 64;
        const bool more = nk < K;
        if (more) {                     // issue next-tile stage (stays in flight)
            if (A_F32) load_a_f32(nk); else stage_a_bf(cur ^ 1, nk);
            stage_b(cur ^ 1, nk);
        }
        if (tt > 0) {                   // B1: stage(t) complete across all waves
            if (more) { if (A_F32) { WAITV(8); } else { WAITV(6); } }
            else      { WAITV(0); }
            BARR();
        }
        compute(cur);
        if (A_F32 && more) {            // T14 late write of next A tile
            WAITV(4);                   // next A regs ready (B(t+1) in flight)
            write_a_f32(cur ^ 1);
            WAITL0();
        }
        if (more) BARR();               // B2: reads of buf[cur] done (self-drained)
        cur ^= 1;
    }

    float bv4[4];
#pragma unroll
    for (int j = 0; j < 4; j++) bv4[j] = bias[n0 + wc * 64 + j * 16 + lrow];

#pragma unroll
    for (int i = 0; i < MI; i++) {
#pragma unroll
        for (int j = 0; j < 4; j++) {
            const int col = n0 + wc * 64 + j * 16 + lrow;
            if (!TRANS) {
#pragma unroll
                for (int r = 0; r < 4; r++) {
                    float x = acc[i][j][r] + bv4[j];
                    if (ACT == 1) x = fmaxf(x, 0.f);
                    if (ACT == 2) x = 1.f / (1.f + __expf(-x));
                    const int row = m0 + wr * (BM / 2) + i * 16 + quad * 4 + r;
                    if (OUT_F32) ((float*)Cvp)[(size_t)row * N + col] = x;
                    else         ((u16*)Cvp)[(size_t)row * N + col] = f2bf(x);
                }
            } else {
                u16 vv[4];
#pragma unroll
                for (int r = 0; r < 4; r++) vv[r] = f2bf(acc[i][j][r] + bv4[j]);
                u16* Cb = (u16*)Cvp;
                size_t base = (size_t)(m0 >> 11) * ((size_t)N * 2048) + (size_t)col * 2048 +
                              (m0 & 2047) + wr * (BM / 2) + i * 16 + quad * 4;
                *(uint32_t*)&Cb[base]     = (uint32_t)vv[0] | ((uint32_t)vv[1] << 16);
                *(uint32_t*)&Cb[base + 2] = (uint32_t)vv[2] | ((uint32_t)vv[3] << 16);
            }
        }
    }
}

// ---------------------------------------------------------------------------
// Flash attention: block = (batch, 64 Q rows); 32 KV tiles of 64; all bf16 in ws.
// LDS 48KB. Wave w owns Q rows 16w..16w+15 (private qp region).
// LDS XOR swizzle (T2, rule #21 both-sides form): physical = logical XOR
// ((row&7)<<4 bytes); gl_lds16 writes linearly so the swizzle is applied by
// inverse-permuting the per-lane GLOBAL source seg (m173) + XOR on reads.
// (round-2 version: measured 95.0us vs 97.2 for the K-dbuf pipeline variant)
__global__ __launch_bounds__(256)
void flash_attn(const u16* __restrict__ Q, const u16* __restrict__ Kb,
                const u16* __restrict__ VT, u16* __restrict__ O) {
    __shared__ u16 k_sh[64 * 128];    // K tile  [kv][d]   (swizzled)
    __shared__ u16 v_sh[128 * 64];    // V^T tile [d][kv]  (swizzled)
    __shared__ u16 qp_sh[64 * 128];   // Q tile, then P [qrow][kv<64] (swizzled)

    const int t = threadIdx.x, wave = t >> 6, lane = t & 63;
    const int lrow = lane & 15, quad = lane >> 4;
    const int lsw = (lrow & 7) << 3;          // element-XOR for swizzled reads
    const int b = blockIdx.x >> 5, q0 = (blockIdx.x & 31) * 64;

    const u16* qg = Q + (size_t)(b * 2048 + q0) * 128;
#pragma unroll
    for (int it = 0; it < 4; it++) {        // 64x128: 16 segs/row, src-seg swizzle
        int s = it * 256 + t;
        int srcSeg = s ^ ((s >> 4) & 7);
        gl_lds16(qg + (size_t)srcSeg * 8, &qp_sh[(it * 256 + wave * 64) * 8]);
    }
    __syncthreads();
    bf16x8 qf[4];
#pragma unroll
    for (int ks = 0; ks < 4; ks++)
        qf[ks] = *(const bf16x8*)&qp_sh[(((wave * 16 + lrow) * 128) + ks * 32 + quad * 8) ^ lsw];

    f32x4 o_acc[8];
#pragma unroll
    for (int ct = 0; ct < 8; ct++) o_acc[ct] = (f32x4){0.f, 0.f, 0.f, 0.f};
    float m_i[4] = {-1e30f, -1e30f, -1e30f, -1e30f};
    float l_i[4] = {0.f, 0.f, 0.f, 0.f};

    for (int tile = 0; tile < 32; tile++) {
        const u16* kg = Kb + (size_t)(b * 2048 + tile * 64) * 128;   // contiguous 16KB
        const u16* vg = VT + (size_t)b * 262144 + tile * 64;         // [d][2048] rows
#pragma unroll
        for (int it = 0; it < 4; it++) {    // K: 64x128, 16 segs/row, src swizzled
            int s = it * 256 + t;
            int srcSeg = s ^ ((s >> 4) & 7);
            gl_lds16(kg + (size_t)srcSeg * 8, &k_sh[(it * 256 + wave * 64) * 8]);
        }
#pragma unroll
        for (int it = 0; it < 4; it++) {    // V^T: 128 rows x 8 segs, src swizzled
            int s = it * 256 + t;
            int row = s >> 3, c = (s & 7) ^ (row & 7);
            gl_lds16(vg + (size_t)row * 2048 + c * 8,
                     &v_sh[(it * 256 + wave * 64) * 8]);
        }
        __syncthreads();

        // S = Q @ K^T : wave computes 16 rows x 64 cols = 4 C-tiles
        f32x4 s_acc[4];
        __builtin_amdgcn_s_setprio(1);
#pragma unroll
        for (int ct = 0; ct < 4; ct++) {
            f32x4 a = (f32x4){0.f, 0.f, 0.f, 0.f};
#pragma unroll
            for (int ks = 0; ks < 4; ks++) {
                bf16x8 kf = *(const bf16x8*)&k_sh[(((ct * 16 + lrow) * 128) + ks * 32 + quad * 8) ^ lsw];
                a = __builtin_amdgcn_mfma_f32_16x16x32_bf16(qf[ks], kf, a, 0, 0, 0);
            }
            s_acc[ct] = a;
        }
        __builtin_amdgcn_s_setprio(0);

        // online softmax: row = quad*4+r, reduce across the 16 lanes of the quad
        float mnew[4], alpha[4], ps[4];
#pragma unroll
        for (int r = 0; r < 4; r++) {
            float mx = s_acc[0][r];
#pragma unroll
            for (int ct = 1; ct < 4; ct++) mx = fmaxf(mx, s_acc[ct][r]);
#pragma unroll
            for (int d = 8; d >= 1; d >>= 1) mx = fmaxf(mx, __shfl_xor(mx, d, 64));
            mnew[r] = fmaxf(m_i[r], mx);
            alpha[r] = __expf(m_i[r] - mnew[r]);
            m_i[r] = mnew[r];
            ps[r] = 0.f;
        }
#pragma unroll
        for (int ct = 0; ct < 4; ct++)
#pragma unroll
            for (int r = 0; r < 4; r++) {
                float p = __expf(s_acc[ct][r] - mnew[r]);
                ps[r] += p;
                qp_sh[(((wave * 16 + quad * 4 + r) * 128) + ct * 16 + lrow) ^ (((quad * 4 + r) & 7) << 3)] = f2bf(p);
            }
#pragma unroll
        for (int r = 0; r < 4; r++) {
#pragma unroll
            for (int d = 8; d >= 1; d >>= 1) ps[r] += __shfl_xor(ps[r], d, 64);
            l_i[r] = l_i[r] * alpha[r] + ps[r];
        }
#pragma unroll
        for (int ct = 0; ct < 8; ct++)
#pragma unroll
            for (int r = 0; r < 4; r++) o_acc[ct][r] *= alpha[r];

        // O += P @ V ; P read back in A-layout (wave-private rows, DS in-order)
        bf16x8 pfa[2];
#pragma unroll
        for (int ks = 0; ks < 2; ks++)
            pfa[ks] = *(const bf16x8*)&qp_sh[(((wave * 16 + lrow) * 128) + ks * 32 + quad * 8) ^ lsw];
        __builtin_amdgcn_s_setprio(1);
#pragma unroll
        for (int ct = 0; ct < 8; ct++)
#pragma unroll
            for (int ks = 0; ks < 2; ks++) {
                bf16x8 vf = *(const bf16x8*)&v_sh[(((ct * 16 + lrow) * 64) + ks * 32 + quad * 8) ^ lsw];
                o_acc[ct] = __builtin_amdgcn_mfma_f32_16x16x32_bf16(pfa[ks], vf, o_acc[ct], 0, 0, 0);
            }
        __builtin_amdgcn_s_setprio(0);
        __syncthreads();
    }

    float inv_l[4];
#pragma unroll
    for (int r = 0; r < 4; r++) inv_l[r] = 1.f / l_i[r];
#pragma unroll
    for (int ct = 0; ct < 8; ct++)
#pragma unroll
        for (int r = 0; r < 4; r++) {
            const int row = b * 2048 + q0 + wave * 16 + quad * 4 + r;
            O[(size_t)row * 128 + ct * 16 + lrow] = f2bf(o_acc[ct][r] * inv_l[r]);
        }
}

// ---------------------------------------------------------------------------
extern "C" void kernel_launch(void* const* d_in, const int* in_sizes, int n_in,
                              void* d_out, int out_size, void* d_ws, size_t ws_size,
                              hipStream_t stream) {
    const float* mainf = (const float*)d_in[0];
    const float* feat  = (const float*)d_in[1];
    const float* We1 = (const float*)d_in[2];  const float* be1 = (const float*)d_in[3];
    const float* We2 = (const float*)d_in[4];  const float* be2 = (const float*)d_in[5];
    const float* Wq  = (const float*)d_in[6];  const float* bq  = (const float*)d_in[7];
    const float* Wk  = (const float*)d_in[8];  const float* bk  = (const float*)d_in[9];
    const float* Wv  = (const float*)d_in[10]; const float* bv  = (const float*)d_in[11];
    const float* Wd1 = (const float*)d_in[12]; const float* bd1 = (const float*)d_in[13];
    const float* Wd2 = (const float*)d_in[14]; const float* bd2 = (const float*)d_in[15];

    // ws layout (u16 elements), total 24,641,536 u16 = 49.3 MB
    u16* ws = (u16*)d_ws;
    u16* wt = ws;                 // 524288 (507904 used), transposed bf16 weights
    u16* h1 = wt + 524288;        // 32768x256 enc hidden / dec hidden (bf16)
    u16* mf = h1 + 8388608;       // 32768x128 m-latent, f-latent, then attn out
    u16* qb = mf + 4194304;       // 32768x128
    u16* kb = qb + 4194304;       // 32768x128
    u16* vT = kb + 4194304;       // [16][128][2048]
    u16* wt_e1 = wt, *wt_e2 = wt + 196608, *wt_q = wt + 229376, *wt_k = wt + 245760,
       * wt_v = wt + 262144, *wt_d1 = wt + 278528, *wt_d2 = wt + 311296;

    transpose_all<<<1984, 256, 0, stream>>>(We1, We2, Wq, Wk, Wv, Wd1, Wd2, wt);

    // encode(main): h1 = relu(main@We1+be1); m = relu(h1@We2+be2); q = m@Wq+bq
    gemm_bt<64, 1, false, true,  false><<<dim3(512, 2), 256, 0, stream>>>(mainf, wt_e1, be1, h1, MM, 256, 768);
    gemm_small<128, 256, 1, false><<<256, 512, 0, stream>>>(h1, wt_e2, be2, mf);
    gemm_small<128, 128, 0, false><<<256, 512, 0, stream>>>(mf, wt_q,  bq,  qb);
    // encode(feature): f; k = f@Wk+bk; vT = (f@Wv+bv)^T per batch
    gemm_bt<64, 1, false, true,  false><<<dim3(512, 2), 256, 0, stream>>>(feat, wt_e1, be1, h1, MM, 256, 768);
    gemm_small<128, 256, 1, false><<<256, 512, 0, stream>>>(h1, wt_e2, be2, mf);
    gemm_small<128, 128, 0, false><<<256, 512, 0, stream>>>(mf, wt_k,  bk,  kb);
    gemm_small<128, 128, 0, true ><<<256, 512, 0, stream>>>(mf, wt_v,  bv,  vT);

    flash_attn<<<512, 256, 0, stream>>>(qb, kb, vT, mf);   // attn -> mf (k,v done)

    // decode: h1 = relu(attn@Wd1+bd1); out = sigmoid(h1@Wd2+bd2) -> fp32 d_out
    gemm_small<256, 128, 1, false><<<256, 512, 0, stream>>>(mf, wt_d1, bd1, h1);
    gemm_bt<64, 2, false, false, true ><<<dim3(512, 6), 256, 0, stream>>>(h1, wt_d2, bd2, d_out, MM, 768, 256);
}